// Round 9
// baseline (2489.506 us; speedup 1.0000x reference)
//
#include <hip/hip_runtime.h>
#include <math.h>

// Problem constants
constexpr int B  = 32;
constexpr int T  = 24;
constexpr int D  = 13;
constexpr int N  = 1024;   // 32*32 spatial
constexpr int SZ = B * D * N;
constexpr int HPW = B * N * 16 / 2;   // hp size in floats (bf16 [B][N][16])
constexpr int GRID = 512;             // persistent kernel: 16 x 32, all co-resident

typedef __attribute__((ext_vector_type(8))) short bf16x8;
typedef __attribute__((ext_vector_type(4))) float f32x4;

__device__ __forceinline__ float sigmoidf_(float x) { return 1.f / (1.f + __expf(-x)); }
__device__ __forceinline__ float tanhf_(float x) {
    float e = __expf(2.f * x);
    return 1.f - 2.f / (e + 1.f);
}
__device__ __forceinline__ unsigned short f2bf(float f) {
    unsigned u = __float_as_uint(f);
    u += 0x8000u;
    return (unsigned short)(u >> 16);
}
__device__ __forceinline__ unsigned pk2bf(float lo, float hi) {
    unsigned a = __float_as_uint(lo) + 0x8000u;
    unsigned b = __float_as_uint(hi) + 0x8000u;
    return __builtin_amdgcn_perm(b, a, 0x07060302u);
}

// grid sync: monotonic counter, agent-scope release/acquire (L2 wb/inv on gfx950)
__device__ __forceinline__ void gsync(unsigned* cnt, unsigned target) {
    __syncthreads();                      // drains each wave's vmcnt before barrier
    if (threadIdx.x == 0) {
        __hip_atomic_fetch_add(cnt, 1u, __ATOMIC_RELEASE, __HIP_MEMORY_SCOPE_AGENT);
        while (__hip_atomic_load(cnt, __ATOMIC_RELAXED, __HIP_MEMORY_SCOPE_AGENT) < target)
            __builtin_amdgcn_s_sleep(16);
        __builtin_amdgcn_fence(__ATOMIC_ACQUIRE, "agent");
    }
    __syncthreads();
}

// ---------------------------------------------------------------- zero init
__global__ void k_zero(float* __restrict__ p, int n) {
    int i = blockIdx.x * 256 + threadIdx.x;
    if (i < n) p[i] = 0.f;
}

// ---------------------------------------------------------------- x1 -> packed bf16 [b][t][pix][16] (one-time)
__global__ __launch_bounds__(256) void k_xprep(const float* __restrict__ x1,
                                               unsigned short* __restrict__ x1p) {
    int i = blockIdx.x * 256 + threadIdx.x;
    int pix = i & 1023, bt = i >> 10;
    const float* src = x1 + (size_t)bt * D * N + pix;
    unsigned short tmp[16];
#pragma unroll
    for (int d = 0; d < 13; ++d) tmp[d] = f2bf(src[(size_t)d * N]);
    tmp[13] = tmp[14] = tmp[15] = 0;
    uint4* dst = (uint4*)(x1p + (size_t)i * 16);
    dst[0] = ((const uint4*)tmp)[0];
    dst[1] = ((const uint4*)tmp)[1];
}

// ---------------------------------------------------------------- conv weights -> MFMA A-fragment layout (bf16)
__global__ void k_wprep(const float* __restrict__ Wg, unsigned short* __restrict__ wrA) {
    int i = blockIdx.x * 256 + threadIdx.x;
    if (i >= 4 * 9 * 64 * 8) return;
    int j = i & 7; int r = i >> 3;
    int lane = r & 63; r >>= 6;
    int tap = r % 9; int ct = r / 9;
    int m = lane & 15, g = lane >> 4;
    int k = g * 8 + j;
    int co = ct * 16 + m;
    int ci = -1;
    if (k < 13) ci = k;
    else if (k >= 16 && k < 29) ci = k - 3;
    unsigned short v = 0;
    if (co < 52 && ci >= 0) v = f2bf(Wg[(co * 26 + ci) * 9 + tap]);
    wrA[i] = v;
}

// LDS union: CP phase and ATTN phase reuse the same 28.9 KB
struct __align__(16) SharedCP {
    unsigned short s_in[136 * 32];   // 8704 B
    float s_g[52 * 65];              // 13520 B
    float s_ht[13 * 64];             // 3328 B
    float s_mv[13 * 64];             // 3328 B
};
struct __align__(16) SharedAT {
    unsigned short s_k[2 * 128 * 24];  // 12288 B
    unsigned short s_v[2 * 16 * 136];  // 8704 B
    unsigned short s_hout[32 * 16];    // 1024 B
    float s_hf[13 * 33];
    float s_zh[13 * 33];
    float s_zm[13 * 33];
    float s_zc[13 * 33];               // 4 x 1716 B
};
union SharedU { SharedCP cp; SharedAT at; };

// ---------------------------------------------------------------- persistent fused sequence kernel
// grid (16,32) = 512 blocks, ALL co-resident (launch_bounds(256,2): <=256 VGPR;
// LDS ~34 KB -> >=2 blocks/CU). Block (i,b) owns pixels [64i,64i+64) of batch b
// in both phases -> c/m/qT/h_tmp are block-private. Cross-block tensors: K/V
// (sync A, double-buffered by t-parity vs WAR) and hp halo (sync B).
__global__ __launch_bounds__(256, 2) void k_seq(
    const unsigned short* __restrict__ x1p, const unsigned short* __restrict__ wrA,
    float* __restrict__ c, float* __restrict__ m, unsigned short* __restrict__ hp,
    float* __restrict__ h_tmp, unsigned short* __restrict__ qT,
    unsigned short* __restrict__ khT, unsigned short* __restrict__ kmT,
    unsigned short* __restrict__ vhb, unsigned short* __restrict__ vmb,
    const float* __restrict__ Wq, const float* __restrict__ Wkh, const float* __restrict__ Wvh,
    const float* __restrict__ Wkm, const float* __restrict__ Wvm,
    const float* __restrict__ Wz, const float* __restrict__ Wm,
    const float* __restrict__ Wf, const float* __restrict__ bfin,
    float* __restrict__ out, unsigned* __restrict__ cnt)
{
    __shared__ SharedU u;
    __shared__ float s_wz[13 * 26];
    __shared__ float s_wm[39 * 26];

    const int bx = blockIdx.x, by = blockIdx.y;
    const int tid = threadIdx.x;
    const int w = __builtin_amdgcn_readfirstlane(tid >> 6);
    const int lane = tid & 63;
    const int g = lane >> 4, l15 = lane & 15;
    const size_t bb = (size_t)by * D * N;

    // persistent weight staging (read in attn epilogue, first use after gsync)
    for (int idx = tid; idx < 13 * 26; idx += 256) s_wz[idx] = Wz[idx];
    for (int idx = tid; idx < 39 * 26; idx += 256) s_wm[idx] = Wm[idx];

    unsigned target = 0;

    for (int t = 0; t < T; ++t) {
        const int par = t & 1;
        // ================= CP PHASE =================
        {
            unsigned short* s_in = u.cp.s_in;
            float* s_g  = u.cp.s_g;
            float* s_ht = u.cp.s_ht;
            float* s_mv = u.cp.s_mv;
            unsigned short* khw = khT + (size_t)par * 16 * B * N;
            unsigned short* kmw = kmT + (size_t)par * 16 * B * N;
            unsigned short* vhw = vhb + (size_t)par * 13 * B * N;
            unsigned short* vmw = vmb + (size_t)par * 13 * B * N;
            const int y = bx * 2 + (lane >> 5), x = lane & 31;
            const int pix = y * 32 + x;

            // prefetch c, m for the pointwise phase
            float cpre[4], mpre[4];
#pragma unroll
            for (int i2 = 0; i2 < 4; ++i2) {
                int dd = w + 4 * i2;
                if (dd < 13) {
                    cpre[i2] = c[bb + (size_t)dd * N + pix];
                    mpre[i2] = m[bb + (size_t)dd * N + pix];
                } else { cpre[i2] = 0.f; mpre[i2] = 0.f; }
            }
            // this wave's 9 A-fragments (co-tile = w)
            bf16x8 af[9];
#pragma unroll
            for (int tap = 0; tap < 9; ++tap)
                af[tap] = *(const bf16x8*)&wrA[(((size_t)w * 9 + tap) * 64 + lane) * 8];

            // stage input tile: 4 rows (2bx-1..2bx+2) x 34 cols, packed bf16
            if (tid < 136) {
                int row = tid / 34, col = tid % 34;
                int gy = bx * 2 - 1 + row, gx = col - 1;
                bool ok = ((unsigned)gy < 32u) && ((unsigned)gx < 32u);
                uint4 z = {0, 0, 0, 0};
                uint4 a0 = z, a1 = z, b0 = z, b1 = z;
                if (ok) {
                    const int off = gy * 32 + gx;
                    const uint4* xs = (const uint4*)(x1p + (((size_t)by * T + t) * N + off) * 16);
                    a0 = xs[0]; a1 = xs[1];
                    const uint4* hs = (const uint4*)(hp + ((size_t)by * N + off) * 16);
                    b0 = hs[0]; b1 = hs[1];
                }
                uint4* dst = (uint4*)&s_in[tid * 32];
                dst[0] = a0; dst[1] = a1; dst[2] = b0; dst[3] = b1;
            }
            __syncthreads();

            // MFMA conv: 4 px-tiles x 9 taps
            f32x4 acc[4];
#pragma unroll
            for (int pt = 0; pt < 4; ++pt) acc[pt] = f32x4{0.f, 0.f, 0.f, 0.f};
#pragma unroll
            for (int pt = 0; pt < 4; ++pt) {
                const int px = pt * 16 + l15;
                const int r0 = px >> 5, c0 = px & 31;
#pragma unroll
                for (int tap = 0; tap < 9; ++tap) {
                    const int srow = r0 + tap / 3, scol = c0 + tap % 3;
                    bf16x8 bfr = *(const bf16x8*)&s_in[(srow * 34 + scol) * 32 + 8 * g];
                    acc[pt] = __builtin_amdgcn_mfma_f32_16x16x32_bf16(af[tap], bfr, acc[pt], 0, 0, 0);
                }
            }
#pragma unroll
            for (int pt = 0; pt < 4; ++pt) {
#pragma unroll
                for (int rr = 0; rr < 4; ++rr) {
                    const int co = w * 16 + 4 * g + rr;
                    if (co < 52) s_g[co * 65 + pt * 16 + l15] = acc[pt][rr];
                }
            }
            __syncthreads();

            // LSTM pointwise (prefetched c/m)
#pragma unroll
            for (int i2 = 0; i2 < 4; ++i2) {
                int dd = w + 4 * i2;
                if (dd < 13) {
                    float ig = sigmoidf_(s_g[dd * 65 + lane]);
                    float fg = sigmoidf_(s_g[(13 + dd) * 65 + lane]);
                    float gg = tanhf_(s_g[(26 + dd) * 65 + lane]);
                    float og = sigmoidf_(s_g[(39 + dd) * 65 + lane]);
                    const size_t gi = bb + (size_t)dd * N + pix;
                    float cn = fg * cpre[i2] + ig * gg;
                    c[gi] = cn;
                    float hv = og * tanhf_(cn);
                    h_tmp[gi] = hv;
                    s_ht[dd * 64 + lane] = hv;
                    s_mv[dd * 64 + lane] = mpre[i2];
                }
            }
            __syncthreads();

            // projections (weights wave-uniform -> s_load)
            const size_t ro = ((size_t)by * N + pix) * 16;
            if (w == 0) {               // q -> qT (scaled by log2e)
                float htv[13];
#pragma unroll
                for (int j = 0; j < 13; ++j) htv[j] = s_ht[j * 64 + lane];
                float o[13];
#pragma unroll
                for (int d = 0; d < 13; ++d) {
                    float a = 0.f;
#pragma unroll
                    for (int j = 0; j < 13; ++j) a = fmaf(Wq[d * 13 + j], htv[j], a);
                    o[d] = a * 1.44269504089f;
                }
                uint4 w0, w1;
                w0.x = pk2bf(o[0], o[1]);  w0.y = pk2bf(o[2], o[3]);
                w0.z = pk2bf(o[4], o[5]);  w0.w = pk2bf(o[6], o[7]);
                w1.x = pk2bf(o[8], o[9]);  w1.y = pk2bf(o[10], o[11]);
                w1.z = pk2bf(o[12], 0.f);  w1.w = 0u;
                ((uint4*)(qT + ro))[0] = w0; ((uint4*)(qT + ro))[1] = w1;
            } else if (w == 1) {        // kh -> khw, vh
                float htv[13];
#pragma unroll
                for (int j = 0; j < 13; ++j) htv[j] = s_ht[j * 64 + lane];
                float o[13];
#pragma unroll
                for (int d = 0; d < 13; ++d) {
                    float a = 0.f;
#pragma unroll
                    for (int j = 0; j < 13; ++j) a = fmaf(Wkh[d * 13 + j], htv[j], a);
                    o[d] = a;
                }
                uint4 w0, w1;
                w0.x = pk2bf(o[0], o[1]);  w0.y = pk2bf(o[2], o[3]);
                w0.z = pk2bf(o[4], o[5]);  w0.w = pk2bf(o[6], o[7]);
                w1.x = pk2bf(o[8], o[9]);  w1.y = pk2bf(o[10], o[11]);
                w1.z = pk2bf(o[12], 0.f);  w1.w = 0u;
                ((uint4*)(khw + ro))[0] = w0; ((uint4*)(khw + ro))[1] = w1;
#pragma unroll
                for (int d = 0; d < 13; ++d) {
                    float a = 0.f;
#pragma unroll
                    for (int j = 0; j < 13; ++j) a = fmaf(Wvh[d * 13 + j], htv[j], a);
                    vhw[bb + (size_t)d * N + pix] = f2bf(a);
                }
            } else if (w == 2) {        // km -> kmw, vm
                float mvv[13];
#pragma unroll
                for (int j = 0; j < 13; ++j) mvv[j] = s_mv[j * 64 + lane];
                float o[13];
#pragma unroll
                for (int d = 0; d < 13; ++d) {
                    float a = 0.f;
#pragma unroll
                    for (int j = 0; j < 13; ++j) a = fmaf(Wkm[d * 13 + j], mvv[j], a);
                    o[d] = a;
                }
                uint4 w0, w1;
                w0.x = pk2bf(o[0], o[1]);  w0.y = pk2bf(o[2], o[3]);
                w0.z = pk2bf(o[4], o[5]);  w0.w = pk2bf(o[6], o[7]);
                w1.x = pk2bf(o[8], o[9]);  w1.y = pk2bf(o[10], o[11]);
                w1.z = pk2bf(o[12], 0.f);  w1.w = 0u;
                ((uint4*)(kmw + ro))[0] = w0; ((uint4*)(kmw + ro))[1] = w1;
#pragma unroll
                for (int d = 0; d < 13; ++d) {
                    float a = 0.f;
#pragma unroll
                    for (int j = 0; j < 13; ++j) a = fmaf(Wvm[d * 13 + j], mvv[j], a);
                    vmw[bb + (size_t)d * N + pix] = f2bf(a);
                }
            }
        }

        if (t == T - 1) break;    // last step: only c is needed downstream

        target += GRID; gsync(cnt, target);   // sync A: K/V/h_tmp visible

        // ================= ATTN PHASE (2 qtiles sequential) =================
        {
            unsigned short* s_k = u.at.s_k;
            unsigned short* s_v = u.at.s_v;
            unsigned short* s_hout = u.at.s_hout;
            float* s_hf = u.at.s_hf;
            float* s_zh = u.at.s_zh;
            float* s_zm = u.at.s_zm;
            float* s_zc = u.at.s_zc;
            const unsigned short* khp_ = khT + (size_t)par * 16 * B * N;
            const unsigned short* kmp_ = kmT + (size_t)par * 16 * B * N;
            const unsigned short* vhp_ = vhb + (size_t)par * 13 * B * N;
            const unsigned short* vmp_ = vmb + (size_t)par * 13 * B * N;
            const int br = w >> 1, qg = w & 1;

            for (int qt = 0; qt < 2; ++qt) {
                __syncthreads();
                const int n0 = bx * 64 + qt * 32;

                for (int idx = tid; idx < 13 * 32; idx += 256) {
                    int d = idx >> 5, p = idx & 31;
                    s_hf[d * 33 + p] = h_tmp[bb + (size_t)d * N + n0 + p];
                }
                for (int idx = tid; idx < 512; idx += 256) s_hout[idx] = 0;
                for (int idx = tid; idx < 2 * 3 * 136; idx += 256) {
                    int keyp = idx % 136;
                    int r = idx / 136;
                    int row = r % 3, br2 = r / 3;
                    s_v[br2 * 2176 + (13 + row) * 136 + keyp] =
                        (row == 0) ? (unsigned short)0x3F80 : (unsigned short)0;
                }

                bf16x8 b1 = {0, 0, 0, 0, 0, 0, 0, 0};
                if (g < 2)
                    b1 = *(const bf16x8*)(qT + ((size_t)by * N + n0 + qg * 16 + l15) * 16 + 8 * g);

                const int rowk = tid >> 1, partk = tid & 1;
                const unsigned short* kb0 = khp_ + ((size_t)by * N + rowk) * 16 + partk * 8;
                const unsigned short* kb1 = kmp_ + ((size_t)by * N + rowk) * 16 + partk * 8;
                unsigned short* sk0 = &s_k[rowk * 24 + partk * 8];
                unsigned short* sk1 = &s_k[3072 + rowk * 24 + partk * 8];
                const int brv0 = (tid >= 208) ? 1 : 0;
                const int rem0 = tid - 208 * brv0;
                const int dv0 = rem0 >> 4, pv0 = rem0 & 15;
                const unsigned short* vb0 = (brv0 ? vmp_ : vhp_) + bb + (size_t)dv0 * N + pv0 * 8;
                unsigned short* sv0 = &s_v[brv0 * 2176 + dv0 * 136 + pv0 * 8];
                const bool doV1 = (tid < 160);
                const int rem1 = tid + 48;
                const int dv1 = rem1 >> 4, pv1 = rem1 & 15;
                const unsigned short* vb1 = vmp_ + bb + (size_t)dv1 * N + pv1 * 8;
                unsigned short* sv1 = &s_v[2176 + dv1 * 136 + pv1 * 8];

                uint4 rk0 = *(const uint4*)kb0;
                uint4 rk1 = *(const uint4*)kb1;
                uint4 rv0 = *(const uint4*)vb0;
                uint4 rv1 = doV1 ? *(const uint4*)vb1 : uint4{0, 0, 0, 0};

                f32x4 zacc = {0.f, 0.f, 0.f, 0.f};

                for (int cc = 0; cc < 8; ++cc) {
                    if (cc) __syncthreads();
                    *(uint4*)sk0 = rk0;
                    *(uint4*)sk1 = rk1;
                    *(uint4*)sv0 = rv0;
                    if (doV1) *(uint4*)sv1 = rv1;
                    __syncthreads();
                    if (cc < 7) {
                        const size_t ko = (size_t)(cc + 1) * 128 * 16;
                        const size_t vo = (size_t)(cc + 1) * 128;
                        rk0 = *(const uint4*)(kb0 + ko);
                        rk1 = *(const uint4*)(kb1 + ko);
                        rv0 = *(const uint4*)(vb0 + vo);
                        if (doV1) rv1 = *(const uint4*)(vb1 + vo);
                    }
#pragma unroll
                    for (int uu = 0; uu < 4; ++uu) {
                        bf16x8 a0 = {0, 0, 0, 0, 0, 0, 0, 0}, a1v = {0, 0, 0, 0, 0, 0, 0, 0};
                        if (g < 2) {
                            const int rbase = 32 * uu + 8 * (l15 >> 2) + (l15 & 3);
                            a0  = *(const bf16x8*)&s_k[br * 3072 + (rbase)     * 24 + 8 * g];
                            a1v = *(const bf16x8*)&s_k[br * 3072 + (rbase + 4) * 24 + 8 * g];
                        }
                        f32x4 d0 = {0.f, 0.f, 0.f, 0.f}, d1 = {0.f, 0.f, 0.f, 0.f};
                        d0 = __builtin_amdgcn_mfma_f32_16x16x32_bf16(a0,  b1, d0, 0, 0, 0);
                        d1 = __builtin_amdgcn_mfma_f32_16x16x32_bf16(a1v, b1, d1, 0, 0, 0);

                        float e0[4], e1[4];
#pragma unroll
                        for (int r = 0; r < 4; ++r) { e0[r] = exp2f(d0[r]); e1[r] = exp2f(d1[r]); }

                        union { int4 iv; bf16x8 v; } u2;
                        u2.iv.x = (int)pk2bf(e0[0], e0[1]);
                        u2.iv.y = (int)pk2bf(e0[2], e0[3]);
                        u2.iv.z = (int)pk2bf(e1[0], e1[1]);
                        u2.iv.w = (int)pk2bf(e1[2], e1[3]);

                        bf16x8 a2 = *(const bf16x8*)&s_v[br * 2176 + l15 * 136 + 32 * uu + 8 * g];
                        zacc = __builtin_amdgcn_mfma_f32_16x16x32_bf16(a2, u2.v, zacc, 0, 0, 0);
                    }
                }

                const float den = __shfl(zacc[1], 48 + l15, 64);
                const float rd = 1.f / den;

                float* zs = br ? s_zm : s_zh;
                const int q = qg * 16 + l15;
#pragma unroll
                for (int r = 0; r < 4; ++r) {
                    int d = 4 * g + r;
                    if (d < 13) zs[d * 33 + q] = zacc[r] * rd;
                }
                __syncthreads();

                for (int idx = tid; idx < 416; idx += 256) {
                    int d = idx >> 5, p = idx & 31;
                    float a = 0.f;
#pragma unroll
                    for (int ci = 0; ci < 13; ++ci)
                        a += s_wz[d * 26 + ci] * s_zh[ci * 33 + p]
                           + s_wz[d * 26 + 13 + ci] * s_zm[ci * 33 + p];
                    s_zc[d * 33 + p] = a;
                }
                __syncthreads();

                for (int idx = tid; idx < 416; idx += 256) {
                    int d = idx >> 5, p = idx & 31;
                    float mo = 0.f, mg = 0.f, mi = 0.f;
#pragma unroll
                    for (int ci = 0; ci < 13; ++ci) {
                        float zc = s_zc[ci * 33 + p];
                        mo += s_wm[d * 26 + ci] * zc;
                        mg += s_wm[(13 + d) * 26 + ci] * zc;
                        mi += s_wm[(26 + d) * 26 + ci] * zc;
                    }
#pragma unroll
                    for (int ci = 0; ci < 13; ++ci) {
                        float hc = s_hf[ci * 33 + p];
                        mo += s_wm[d * 26 + 13 + ci] * hc;
                        mg += s_wm[(13 + d) * 26 + 13 + ci] * hc;
                        mi += s_wm[(26 + d) * 26 + 13 + ci] * hc;
                    }
                    mi = sigmoidf_(mi);
                    const size_t gi = bb + (size_t)d * N + n0 + p;
                    float mn = (1.f - mi) * m[gi] + mi * tanhf_(mg);
                    m[gi] = mn;
                    s_hout[p * 16 + d] = f2bf(sigmoidf_(mo) * mn);
                }
                __syncthreads();

                if (tid < 32) {
                    uint4* dst = (uint4*)(hp + ((size_t)by * N + n0 + tid) * 16);
                    const uint4* srcp = (const uint4*)&s_hout[tid * 16];
                    dst[0] = srcp[0]; dst[1] = srcp[1];
                }
            }
        }

        target += GRID; gsync(cnt, target);   // sync B: hp halo visible
    }

    // ================= FINAL: 1x1 conv + log_softmax (c is block-private) =================
    __syncthreads();
    if (tid < 64) {
        const int px = bx * 64 + tid;
        const size_t base = bb + px;
        float cv[13];
#pragma unroll
        for (int d = 0; d < 13; ++d) cv[d] = c[base + (size_t)d * N];
        float lg[8]; float mx = -1e30f;
#pragma unroll
        for (int k = 0; k < 8; ++k) {
            float a = bfin[k];
#pragma unroll
            for (int d = 0; d < 13; ++d) a += Wf[k * 13 + d] * cv[d];
            lg[k] = a; mx = fmaxf(mx, a);
        }
        float s = 0.f;
#pragma unroll
        for (int k = 0; k < 8; ++k) s += __expf(lg[k] - mx);
        float lse = mx + logf(s);
        const size_t ob = (size_t)by * 8 * N + px;
#pragma unroll
        for (int k = 0; k < 8; ++k) out[ob + (size_t)k * N] = lg[k] - lse;
    }
}

// ---------------------------------------------------------------- host launcher
extern "C" void kernel_launch(void* const* d_in, const int* in_sizes, int n_in,
                              void* d_out, int out_size, void* d_ws, size_t ws_size,
                              hipStream_t stream) {
    const float* x1  = (const float*)d_in[0];
    const float* Wg  = (const float*)d_in[1];
    const float* Wq  = (const float*)d_in[2];
    const float* Wkh = (const float*)d_in[3];
    const float* Wvh = (const float*)d_in[4];
    const float* Wkm = (const float*)d_in[5];
    const float* Wvm = (const float*)d_in[6];
    const float* Wz  = (const float*)d_in[7];
    const float* Wm  = (const float*)d_in[8];
    const float* Wf  = (const float*)d_in[9];
    const float* bf  = (const float*)d_in[10];

    float* ws = (float*)d_ws;
    unsigned* cnt = (unsigned*)d_ws;                        // ws[0..64): counter + pad
    float* c   = ws + 64;
    float* m   = ws + 64 + (size_t)SZ;
    unsigned short* hp = (unsigned short*)(ws + 64 + 2 * (size_t)SZ);
    float* h_tmp = ws + 64 + 2 * (size_t)SZ + HPW;

    unsigned short* qT  = (unsigned short*)(h_tmp + (size_t)SZ);
    unsigned short* khT = qT  + (size_t)16 * B * N;         // [2][B][N][16]
    unsigned short* kmT = khT + (size_t)32 * B * N;         // [2][B][N][16]
    unsigned short* vhb = kmT + (size_t)32 * B * N;         // [2][B][13][N]
    unsigned short* vmb = vhb + (size_t)26 * B * N;         // [2][B][13][N]
    unsigned short* x1p = vmb + (size_t)26 * B * N;         // [B][T][N][16]
    unsigned short* wrA = x1p + (size_t)16 * B * T * N;     // A-frags

    // zero counter + c + m + hp (contiguous)
    const int zn = 64 + 2 * SZ + HPW;
    k_zero<<<(zn + 255) / 256, 256, 0, stream>>>(ws, zn);
    k_wprep<<<72, 256, 0, stream>>>(Wg, wrA);
    k_xprep<<<(B * T * N) / 256, 256, 0, stream>>>(x1, x1p);

    k_seq<<<dim3(16, 32), 256, 0, stream>>>(x1p, wrA, c, m, hp, h_tmp,
                                            qT, khT, kmT, vhb, vmb,
                                            Wq, Wkh, Wvh, Wkm, Wvm, Wz, Wm,
                                            Wf, bf, (float*)d_out, cnt);
}

// Round 10
// 1175.295 us; speedup vs baseline: 2.1182x; 2.1182x over previous
//
#include <hip/hip_runtime.h>
#include <math.h>

// Problem constants
constexpr int B  = 32;
constexpr int T  = 24;
constexpr int D  = 13;
constexpr int N  = 1024;   // 32*32 spatial
constexpr int SZ = B * D * N;
constexpr int HPW = B * N * 16 / 2;   // hp size in floats (bf16 [B][N][16])

typedef __attribute__((ext_vector_type(8))) short bf16x8;
typedef __attribute__((ext_vector_type(4))) float f32x4;

__device__ __forceinline__ float sigmoidf_(float x) { return 1.f / (1.f + __expf(-x)); }
__device__ __forceinline__ float tanhf_(float x) {
    float e = __expf(2.f * x);
    return 1.f - 2.f / (e + 1.f);
}
__device__ __forceinline__ unsigned short f2bf(float f) {
    unsigned u = __float_as_uint(f);
    u += 0x8000u;
    return (unsigned short)(u >> 16);
}
__device__ __forceinline__ unsigned pk2bf(float lo, float hi) {
    unsigned a = __float_as_uint(lo) + 0x8000u;
    unsigned b = __float_as_uint(hi) + 0x8000u;
    return __builtin_amdgcn_perm(b, a, 0x07060302u);
}

// ---- agent-scope (sc1, L2-bypass) accessors for cross-block data ----
__device__ __forceinline__ uint4 aload16(const unsigned short* p) {
    const unsigned long long* q = (const unsigned long long*)p;
    unsigned long long a = __hip_atomic_load(q,     __ATOMIC_RELAXED, __HIP_MEMORY_SCOPE_AGENT);
    unsigned long long b = __hip_atomic_load(q + 1, __ATOMIC_RELAXED, __HIP_MEMORY_SCOPE_AGENT);
    uint4 r;
    r.x = (unsigned)a; r.y = (unsigned)(a >> 32);
    r.z = (unsigned)b; r.w = (unsigned)(b >> 32);
    return r;
}
__device__ __forceinline__ void astore16(unsigned short* p, uint4 v) {
    unsigned long long* q = (unsigned long long*)p;
    unsigned long long a = ((unsigned long long)v.y << 32) | v.x;
    unsigned long long b = ((unsigned long long)v.w << 32) | v.z;
    __hip_atomic_store(q,     a, __ATOMIC_RELAXED, __HIP_MEMORY_SCOPE_AGENT);
    __hip_atomic_store(q + 1, b, __ATOMIC_RELAXED, __HIP_MEMORY_SCOPE_AGENT);
}
__device__ __forceinline__ void astore2(unsigned short* p, unsigned short v) {
    __hip_atomic_store(p, v, __ATOMIC_RELAXED, __HIP_MEMORY_SCOPE_AGENT);
}

// two-level fence-free barrier: cnts[by*16] (16 blocks each) -> cnt2 (32 leaders).
// No release/acquire fences: cross-block data travels via sc1 (L3), and
// __syncthreads drains vmcnt before the signal.
__device__ __forceinline__ void gsync(unsigned* cnts, int bx, int by, unsigned k) {
    __syncthreads();
    if (threadIdx.x == 0) {
        unsigned* c1 = cnts + by * 16;
        unsigned* c2 = cnts + 512;
        __hip_atomic_fetch_add(c1, 1u, __ATOMIC_RELAXED, __HIP_MEMORY_SCOPE_AGENT);
        if (bx == 0) {
            while (__hip_atomic_load(c1, __ATOMIC_RELAXED, __HIP_MEMORY_SCOPE_AGENT) < 16u * k)
                __builtin_amdgcn_s_sleep(2);
            __hip_atomic_fetch_add(c2, 1u, __ATOMIC_RELAXED, __HIP_MEMORY_SCOPE_AGENT);
        }
        while (__hip_atomic_load(c2, __ATOMIC_RELAXED, __HIP_MEMORY_SCOPE_AGENT) < 32u * k)
            __builtin_amdgcn_s_sleep(4);
    }
    __syncthreads();
}

// ---------------------------------------------------------------- zero init
__global__ void k_zero(float* __restrict__ p, int n) {
    int i = blockIdx.x * 256 + threadIdx.x;
    if (i < n) p[i] = 0.f;
}

// ---------------------------------------------------------------- x1 -> packed bf16 [b][t][pix][16] (one-time)
__global__ __launch_bounds__(256) void k_xprep(const float* __restrict__ x1,
                                               unsigned short* __restrict__ x1p) {
    int i = blockIdx.x * 256 + threadIdx.x;
    int pix = i & 1023, bt = i >> 10;
    const float* src = x1 + (size_t)bt * D * N + pix;
    unsigned short tmp[16];
#pragma unroll
    for (int d = 0; d < 13; ++d) tmp[d] = f2bf(src[(size_t)d * N]);
    tmp[13] = tmp[14] = tmp[15] = 0;
    uint4* dst = (uint4*)(x1p + (size_t)i * 16);
    dst[0] = ((const uint4*)tmp)[0];
    dst[1] = ((const uint4*)tmp)[1];
}

// ---------------------------------------------------------------- conv weights -> MFMA A-fragment layout (bf16)
__global__ void k_wprep(const float* __restrict__ Wg, unsigned short* __restrict__ wrA) {
    int i = blockIdx.x * 256 + threadIdx.x;
    if (i >= 4 * 9 * 64 * 8) return;
    int j = i & 7; int r = i >> 3;
    int lane = r & 63; r >>= 6;
    int tap = r % 9; int ct = r / 9;
    int m = lane & 15, g = lane >> 4;
    int k = g * 8 + j;
    int co = ct * 16 + m;
    int ci = -1;
    if (k < 13) ci = k;
    else if (k >= 16 && k < 29) ci = k - 3;
    unsigned short v = 0;
    if (co < 52 && ci >= 0) v = f2bf(Wg[(co * 26 + ci) * 9 + tap]);
    wrA[i] = v;
}

// LDS union: CP phase and ATTN phase reuse the same region
struct __align__(16) SharedCP {
    unsigned short s_in[136 * 32];   // 8704 B
    float s_g[52 * 65];              // 13520 B
    float s_ht[13 * 64];
    float s_mv[13 * 64];
};
struct __align__(16) SharedAT {
    unsigned short s_k[2 * 128 * 24];  // 12288 B
    unsigned short s_v[2 * 16 * 136];  // 8704 B
    unsigned short s_hout[64 * 16];    // 2048 B
    float s_hf[13 * 65];
    float s_zh[13 * 65];
    float s_zm[13 * 65];
    float s_zc[13 * 65];               // 4 x 3380 B
};
union SharedU { SharedCP cp; SharedAT at; };

// ---------------------------------------------------------------- persistent fused sequence kernel
// grid (16,32) = 512 blocks co-resident (2/CU). Block (bx,by) owns pixels
// [64bx,64bx+64) of batch by in BOTH phases -> c/m/qT/h_tmp block-private
// (normal loads, L2-resident forever — no fences anywhere). Cross-block data
// (K/V, hp) goes through L3 via sc1 (agent-scope) accessors only.
__global__ __launch_bounds__(256, 2) void k_seq(
    const unsigned short* __restrict__ x1p, const unsigned short* __restrict__ wrA,
    float* __restrict__ c, float* __restrict__ m, unsigned short* __restrict__ hp,
    float* __restrict__ h_tmp, unsigned short* __restrict__ qT,
    unsigned short* __restrict__ khT, unsigned short* __restrict__ kmT,
    unsigned short* __restrict__ vhb, unsigned short* __restrict__ vmb,
    const float* __restrict__ Wq, const float* __restrict__ Wkh, const float* __restrict__ Wvh,
    const float* __restrict__ Wkm, const float* __restrict__ Wvm,
    const float* __restrict__ Wz, const float* __restrict__ Wm,
    const float* __restrict__ Wf, const float* __restrict__ bfin,
    float* __restrict__ out, unsigned* __restrict__ cnts)
{
    __shared__ SharedU u;
    __shared__ float s_wz[13 * 26];
    __shared__ float s_wm[39 * 26];

    const int bx = blockIdx.x, by = blockIdx.y;
    const int tid = threadIdx.x;
    const int w = __builtin_amdgcn_readfirstlane(tid >> 6);
    const int lane = tid & 63;
    const int g = lane >> 4, l15 = lane & 15;
    const size_t bb = (size_t)by * D * N;

    for (int idx = tid; idx < 13 * 26; idx += 256) s_wz[idx] = Wz[idx];
    for (int idx = tid; idx < 39 * 26; idx += 256) s_wm[idx] = Wm[idx];

    unsigned kk = 0;

    for (int t = 0; t < T; ++t) {
        // ================= CP PHASE =================
        {
            unsigned short* s_in = u.cp.s_in;
            float* s_g  = u.cp.s_g;
            float* s_ht = u.cp.s_ht;
            float* s_mv = u.cp.s_mv;
            const int y = bx * 2 + (lane >> 5), x = lane & 31;
            const int pix = y * 32 + x;

            float cpre[4], mpre[4];
#pragma unroll
            for (int i2 = 0; i2 < 4; ++i2) {
                int dd = w + 4 * i2;
                if (dd < 13) {
                    cpre[i2] = c[bb + (size_t)dd * N + pix];
                    mpre[i2] = m[bb + (size_t)dd * N + pix];
                } else { cpre[i2] = 0.f; mpre[i2] = 0.f; }
            }
            bf16x8 af[9];
#pragma unroll
            for (int tap = 0; tap < 9; ++tap)
                af[tap] = *(const bf16x8*)&wrA[(((size_t)w * 9 + tap) * 64 + lane) * 8];

            // stage input tile: x1p normal loads, hp via sc1 (cross-block halo)
            if (tid < 136) {
                int row = tid / 34, col = tid % 34;
                int gy = bx * 2 - 1 + row, gx = col - 1;
                bool ok = ((unsigned)gy < 32u) && ((unsigned)gx < 32u);
                uint4 z = {0, 0, 0, 0};
                uint4 a0 = z, a1 = z, b0 = z, b1 = z;
                if (ok) {
                    const int off = gy * 32 + gx;
                    const uint4* xs = (const uint4*)(x1p + (((size_t)by * T + t) * N + off) * 16);
                    a0 = xs[0]; a1 = xs[1];
                    const unsigned short* hsp = hp + ((size_t)by * N + off) * 16;
                    b0 = aload16(hsp);
                    b1 = aload16(hsp + 8);
                }
                uint4* dst = (uint4*)&s_in[tid * 32];
                dst[0] = a0; dst[1] = a1; dst[2] = b0; dst[3] = b1;
            }
            __syncthreads();

            f32x4 acc[4];
#pragma unroll
            for (int pt = 0; pt < 4; ++pt) acc[pt] = f32x4{0.f, 0.f, 0.f, 0.f};
#pragma unroll
            for (int pt = 0; pt < 4; ++pt) {
                const int px = pt * 16 + l15;
                const int r0 = px >> 5, c0 = px & 31;
#pragma unroll
                for (int tap = 0; tap < 9; ++tap) {
                    const int srow = r0 + tap / 3, scol = c0 + tap % 3;
                    bf16x8 bfr = *(const bf16x8*)&s_in[(srow * 34 + scol) * 32 + 8 * g];
                    acc[pt] = __builtin_amdgcn_mfma_f32_16x16x32_bf16(af[tap], bfr, acc[pt], 0, 0, 0);
                }
            }
#pragma unroll
            for (int pt = 0; pt < 4; ++pt) {
#pragma unroll
                for (int rr = 0; rr < 4; ++rr) {
                    const int co = w * 16 + 4 * g + rr;
                    if (co < 52) s_g[co * 65 + pt * 16 + l15] = acc[pt][rr];
                }
            }
            __syncthreads();

#pragma unroll
            for (int i2 = 0; i2 < 4; ++i2) {
                int dd = w + 4 * i2;
                if (dd < 13) {
                    float ig = sigmoidf_(s_g[dd * 65 + lane]);
                    float fg = sigmoidf_(s_g[(13 + dd) * 65 + lane]);
                    float gg = tanhf_(s_g[(26 + dd) * 65 + lane]);
                    float og = sigmoidf_(s_g[(39 + dd) * 65 + lane]);
                    const size_t gi = bb + (size_t)dd * N + pix;
                    float cn = fg * cpre[i2] + ig * gg;
                    c[gi] = cn;
                    float hv = og * tanhf_(cn);
                    h_tmp[gi] = hv;
                    s_ht[dd * 64 + lane] = hv;
                    s_mv[dd * 64 + lane] = mpre[i2];
                }
            }
            __syncthreads();

            const size_t ro = ((size_t)by * N + pix) * 16;
            if (w == 0) {               // q -> qT (private, normal stores; log2e folded)
                float htv[13];
#pragma unroll
                for (int j = 0; j < 13; ++j) htv[j] = s_ht[j * 64 + lane];
                float o[13];
#pragma unroll
                for (int d = 0; d < 13; ++d) {
                    float a = 0.f;
#pragma unroll
                    for (int j = 0; j < 13; ++j) a = fmaf(Wq[d * 13 + j], htv[j], a);
                    o[d] = a * 1.44269504089f;
                }
                uint4 w0, w1;
                w0.x = pk2bf(o[0], o[1]);  w0.y = pk2bf(o[2], o[3]);
                w0.z = pk2bf(o[4], o[5]);  w0.w = pk2bf(o[6], o[7]);
                w1.x = pk2bf(o[8], o[9]);  w1.y = pk2bf(o[10], o[11]);
                w1.z = pk2bf(o[12], 0.f);  w1.w = 0u;
                ((uint4*)(qT + ro))[0] = w0; ((uint4*)(qT + ro))[1] = w1;
            } else if (w == 1) {        // kh/vh -> sc1 stores (cross-block)
                float htv[13];
#pragma unroll
                for (int j = 0; j < 13; ++j) htv[j] = s_ht[j * 64 + lane];
                float o[13];
#pragma unroll
                for (int d = 0; d < 13; ++d) {
                    float a = 0.f;
#pragma unroll
                    for (int j = 0; j < 13; ++j) a = fmaf(Wkh[d * 13 + j], htv[j], a);
                    o[d] = a;
                }
                uint4 w0, w1;
                w0.x = pk2bf(o[0], o[1]);  w0.y = pk2bf(o[2], o[3]);
                w0.z = pk2bf(o[4], o[5]);  w0.w = pk2bf(o[6], o[7]);
                w1.x = pk2bf(o[8], o[9]);  w1.y = pk2bf(o[10], o[11]);
                w1.z = pk2bf(o[12], 0.f);  w1.w = 0u;
                astore16(khT + ro, w0); astore16(khT + ro + 8, w1);
#pragma unroll
                for (int d = 0; d < 13; ++d) {
                    float a = 0.f;
#pragma unroll
                    for (int j = 0; j < 13; ++j) a = fmaf(Wvh[d * 13 + j], htv[j], a);
                    astore2(vhb + bb + (size_t)d * N + pix, f2bf(a));
                }
            } else if (w == 2) {        // km/vm -> sc1 stores
                float mvv[13];
#pragma unroll
                for (int j = 0; j < 13; ++j) mvv[j] = s_mv[j * 64 + lane];
                float o[13];
#pragma unroll
                for (int d = 0; d < 13; ++d) {
                    float a = 0.f;
#pragma unroll
                    for (int j = 0; j < 13; ++j) a = fmaf(Wkm[d * 13 + j], mvv[j], a);
                    o[d] = a;
                }
                uint4 w0, w1;
                w0.x = pk2bf(o[0], o[1]);  w0.y = pk2bf(o[2], o[3]);
                w0.z = pk2bf(o[4], o[5]);  w0.w = pk2bf(o[6], o[7]);
                w1.x = pk2bf(o[8], o[9]);  w1.y = pk2bf(o[10], o[11]);
                w1.z = pk2bf(o[12], 0.f);  w1.w = 0u;
                astore16(kmT + ro, w0); astore16(kmT + ro + 8, w1);
#pragma unroll
                for (int d = 0; d < 13; ++d) {
                    float a = 0.f;
#pragma unroll
                    for (int j = 0; j < 13; ++j) a = fmaf(Wvm[d * 13 + j], mvv[j], a);
                    astore2(vmb + bb + (size_t)d * N + pix, f2bf(a));
                }
            }
        }

        if (t == T - 1) break;

        ++kk; gsync(cnts, bx, by, kk);   // sync A: K/V at L3

        // ================= ATTN PHASE (64 queries, single K/V pass) =================
        {
            unsigned short* s_k = u.at.s_k;
            unsigned short* s_v = u.at.s_v;
            unsigned short* s_hout = u.at.s_hout;
            float* s_hf = u.at.s_hf;
            float* s_zh = u.at.s_zh;
            float* s_zm = u.at.s_zm;
            float* s_zc = u.at.s_zc;
            const int br = w >> 1, qg = w & 1;
            const int n0 = bx * 64;

            // staging assignments + initial sc1 prefetch (issue first)
            const int rowk = tid >> 1, partk = tid & 1;
            const unsigned short* kb0 = khT + ((size_t)by * N + rowk) * 16 + partk * 8;
            const unsigned short* kb1 = kmT + ((size_t)by * N + rowk) * 16 + partk * 8;
            unsigned short* sk0 = &s_k[rowk * 24 + partk * 8];
            unsigned short* sk1 = &s_k[3072 + rowk * 24 + partk * 8];
            const int brv0 = (tid >= 208) ? 1 : 0;
            const int rem0 = tid - 208 * brv0;
            const int dv0 = rem0 >> 4, pv0 = rem0 & 15;
            const unsigned short* vb0 = (brv0 ? vmb : vhb) + bb + (size_t)dv0 * N + pv0 * 8;
            unsigned short* sv0 = &s_v[brv0 * 2176 + dv0 * 136 + pv0 * 8];
            const bool doV1 = (tid < 160);
            const int rem1 = tid + 48;
            const int dv1 = rem1 >> 4, pv1 = rem1 & 15;
            const unsigned short* vb1 = vmb + bb + (size_t)dv1 * N + pv1 * 8;
            unsigned short* sv1 = &s_v[2176 + dv1 * 136 + pv1 * 8];

            uint4 rk0 = aload16(kb0);
            uint4 rk1 = aload16(kb1);
            uint4 rv0 = aload16(vb0);
            uint4 rv1 = doV1 ? aload16(vb1) : uint4{0, 0, 0, 0};

            for (int idx = tid; idx < 832; idx += 256) {
                int d = idx >> 6, p = idx & 63;
                s_hf[d * 65 + p] = h_tmp[bb + (size_t)d * N + n0 + p];
            }
            for (int idx = tid; idx < 1024; idx += 256) s_hout[idx] = 0;
            for (int idx = tid; idx < 2 * 3 * 136; idx += 256) {
                int keyp = idx % 136;
                int r = idx / 136;
                int row = r % 3, br2 = r / 3;
                s_v[br2 * 2176 + (13 + row) * 136 + keyp] =
                    (row == 0) ? (unsigned short)0x3F80 : (unsigned short)0;
            }

            // q fragments for this wave's two query groups (qg, qg+2)
            bf16x8 b1a = {0, 0, 0, 0, 0, 0, 0, 0}, b1b = {0, 0, 0, 0, 0, 0, 0, 0};
            if (g < 2) {
                b1a = *(const bf16x8*)(qT + ((size_t)by * N + n0 + qg * 16 + l15) * 16 + 8 * g);
                b1b = *(const bf16x8*)(qT + ((size_t)by * N + n0 + (qg + 2) * 16 + l15) * 16 + 8 * g);
            }

            f32x4 zacca = {0.f, 0.f, 0.f, 0.f}, zaccb = {0.f, 0.f, 0.f, 0.f};

            for (int cc = 0; cc < 8; ++cc) {
                if (cc) __syncthreads();
                *(uint4*)sk0 = rk0;
                *(uint4*)sk1 = rk1;
                *(uint4*)sv0 = rv0;
                if (doV1) *(uint4*)sv1 = rv1;
                __syncthreads();
                if (cc < 7) {
                    const size_t ko = (size_t)(cc + 1) * 128 * 16;
                    const size_t vo = (size_t)(cc + 1) * 128;
                    rk0 = aload16(kb0 + ko);
                    rk1 = aload16(kb1 + ko);
                    rv0 = aload16(vb0 + vo);
                    if (doV1) rv1 = aload16(vb1 + vo);
                }
#pragma unroll
                for (int uu = 0; uu < 4; ++uu) {
                    bf16x8 a0 = {0, 0, 0, 0, 0, 0, 0, 0}, a1v = {0, 0, 0, 0, 0, 0, 0, 0};
                    if (g < 2) {
                        const int rbase = 32 * uu + 8 * (l15 >> 2) + (l15 & 3);
                        a0  = *(const bf16x8*)&s_k[br * 3072 + (rbase)     * 24 + 8 * g];
                        a1v = *(const bf16x8*)&s_k[br * 3072 + (rbase + 4) * 24 + 8 * g];
                    }
                    bf16x8 a2 = *(const bf16x8*)&s_v[br * 2176 + l15 * 136 + 32 * uu + 8 * g];

                    // group A
                    {
                        f32x4 d0 = {0.f, 0.f, 0.f, 0.f}, d1 = {0.f, 0.f, 0.f, 0.f};
                        d0 = __builtin_amdgcn_mfma_f32_16x16x32_bf16(a0,  b1a, d0, 0, 0, 0);
                        d1 = __builtin_amdgcn_mfma_f32_16x16x32_bf16(a1v, b1a, d1, 0, 0, 0);
                        float e0[4], e1[4];
#pragma unroll
                        for (int r = 0; r < 4; ++r) { e0[r] = exp2f(d0[r]); e1[r] = exp2f(d1[r]); }
                        union { int4 iv; bf16x8 v; } u2;
                        u2.iv.x = (int)pk2bf(e0[0], e0[1]);
                        u2.iv.y = (int)pk2bf(e0[2], e0[3]);
                        u2.iv.z = (int)pk2bf(e1[0], e1[1]);
                        u2.iv.w = (int)pk2bf(e1[2], e1[3]);
                        zacca = __builtin_amdgcn_mfma_f32_16x16x32_bf16(a2, u2.v, zacca, 0, 0, 0);
                    }
                    // group B
                    {
                        f32x4 d0 = {0.f, 0.f, 0.f, 0.f}, d1 = {0.f, 0.f, 0.f, 0.f};
                        d0 = __builtin_amdgcn_mfma_f32_16x16x32_bf16(a0,  b1b, d0, 0, 0, 0);
                        d1 = __builtin_amdgcn_mfma_f32_16x16x32_bf16(a1v, b1b, d1, 0, 0, 0);
                        float e0[4], e1[4];
#pragma unroll
                        for (int r = 0; r < 4; ++r) { e0[r] = exp2f(d0[r]); e1[r] = exp2f(d1[r]); }
                        union { int4 iv; bf16x8 v; } u2;
                        u2.iv.x = (int)pk2bf(e0[0], e0[1]);
                        u2.iv.y = (int)pk2bf(e0[2], e0[3]);
                        u2.iv.z = (int)pk2bf(e1[0], e1[1]);
                        u2.iv.w = (int)pk2bf(e1[2], e1[3]);
                        zaccb = __builtin_amdgcn_mfma_f32_16x16x32_bf16(a2, u2.v, zaccb, 0, 0, 0);
                    }
                }
            }

            const float denA = __shfl(zacca[1], 48 + l15, 64);
            const float denB = __shfl(zaccb[1], 48 + l15, 64);
            const float rdA = 1.f / denA, rdB = 1.f / denB;

            float* zs = br ? s_zm : s_zh;
#pragma unroll
            for (int r = 0; r < 4; ++r) {
                int d = 4 * g + r;
                if (d < 13) {
                    zs[d * 65 + qg * 16 + l15]       = zacca[r] * rdA;
                    zs[d * 65 + (qg + 2) * 16 + l15] = zaccb[r] * rdB;
                }
            }
            __syncthreads();

            for (int idx = tid; idx < 832; idx += 256) {
                int d = idx >> 6, p = idx & 63;
                float a = 0.f;
#pragma unroll
                for (int ci = 0; ci < 13; ++ci)
                    a += s_wz[d * 26 + ci] * s_zh[ci * 65 + p]
                       + s_wz[d * 26 + 13 + ci] * s_zm[ci * 65 + p];
                s_zc[d * 65 + p] = a;
            }
            __syncthreads();

            for (int idx = tid; idx < 832; idx += 256) {
                int d = idx >> 6, p = idx & 63;
                float mo = 0.f, mg = 0.f, mi = 0.f;
#pragma unroll
                for (int ci = 0; ci < 13; ++ci) {
                    float zc = s_zc[ci * 65 + p];
                    mo += s_wm[d * 26 + ci] * zc;
                    mg += s_wm[(13 + d) * 26 + ci] * zc;
                    mi += s_wm[(26 + d) * 26 + ci] * zc;
                }
#pragma unroll
                for (int ci = 0; ci < 13; ++ci) {
                    float hc = s_hf[ci * 65 + p];
                    mo += s_wm[d * 26 + 13 + ci] * hc;
                    mg += s_wm[(13 + d) * 26 + 13 + ci] * hc;
                    mi += s_wm[(26 + d) * 26 + 13 + ci] * hc;
                }
                mi = sigmoidf_(mi);
                const size_t gi = bb + (size_t)d * N + n0 + p;
                float mn = (1.f - mi) * m[gi] + mi * tanhf_(mg);
                m[gi] = mn;
                s_hout[p * 16 + d] = f2bf(sigmoidf_(mo) * mn);
            }
            __syncthreads();

            if (tid < 64) {   // hp via sc1 (read cross-block next step)
                unsigned short* dst = hp + ((size_t)by * N + n0 + tid) * 16;
                const uint4* srcp = (const uint4*)&s_hout[tid * 16];
                astore16(dst, srcp[0]);
                astore16(dst + 8, srcp[1]);
            }
        }

        ++kk; gsync(cnts, bx, by, kk);   // sync B: hp at L3
    }

    // ================= FINAL: 1x1 conv + log_softmax (c block-private) =================
    __syncthreads();
    if (tid < 64) {
        const int px = bx * 64 + tid;
        const size_t base = bb + px;
        float cv[13];
#pragma unroll
        for (int d = 0; d < 13; ++d) cv[d] = c[base + (size_t)d * N];
        float lg[8]; float mx = -1e30f;
#pragma unroll
        for (int k = 0; k < 8; ++k) {
            float a = bfin[k];
#pragma unroll
            for (int d = 0; d < 13; ++d) a += Wf[k * 13 + d] * cv[d];
            lg[k] = a; mx = fmaxf(mx, a);
        }
        float s = 0.f;
#pragma unroll
        for (int k = 0; k < 8; ++k) s += __expf(lg[k] - mx);
        float lse = mx + logf(s);
        const size_t ob = (size_t)by * 8 * N + px;
#pragma unroll
        for (int k = 0; k < 8; ++k) out[ob + (size_t)k * N] = lg[k] - lse;
    }
}

// ---------------------------------------------------------------- host launcher
extern "C" void kernel_launch(void* const* d_in, const int* in_sizes, int n_in,
                              void* d_out, int out_size, void* d_ws, size_t ws_size,
                              hipStream_t stream) {
    const float* x1  = (const float*)d_in[0];
    const float* Wg  = (const float*)d_in[1];
    const float* Wq  = (const float*)d_in[2];
    const float* Wkh = (const float*)d_in[3];
    const float* Wvh = (const float*)d_in[4];
    const float* Wkm = (const float*)d_in[5];
    const float* Wvm = (const float*)d_in[6];
    const float* Wz  = (const float*)d_in[7];
    const float* Wm  = (const float*)d_in[8];
    const float* Wf  = (const float*)d_in[9];
    const float* bf  = (const float*)d_in[10];

    float* ws = (float*)d_ws;
    unsigned* cnts = (unsigned*)d_ws;                       // ws[0..1024): counters
    float* c   = ws + 1024;
    float* m   = c + (size_t)SZ;
    unsigned short* hp = (unsigned short*)(m + (size_t)SZ); // [B][N][16] bf16
    float* h_tmp = (float*)(hp + (size_t)2 * HPW);

    unsigned short* qT  = (unsigned short*)(h_tmp + (size_t)SZ);
    unsigned short* khT = qT  + (size_t)16 * B * N;         // [B][N][16]
    unsigned short* kmT = khT + (size_t)16 * B * N;
    unsigned short* vhb = kmT + (size_t)16 * B * N;         // [B][13][N]
    unsigned short* vmb = vhb + (size_t)13 * B * N;
    unsigned short* x1p = vmb + (size_t)13 * B * N;         // [B][T][N][16]
    unsigned short* wrA = x1p + (size_t)16 * B * T * N;

    const int zn = 1024 + 2 * SZ + HPW;    // counters + c + m + hp
    k_zero<<<(zn + 255) / 256, 256, 0, stream>>>(ws, zn);
    k_wprep<<<72, 256, 0, stream>>>(Wg, wrA);
    k_xprep<<<(B * T * N) / 256, 256, 0, stream>>>(x1, x1p);

    k_seq<<<dim3(16, 32), 256, 0, stream>>>(x1p, wrA, c, m, hp, h_tmp,
                                            qT, khT, kmT, vhb, vmb,
                                            Wq, Wkh, Wvh, Wkm, Wvm, Wz, Wm,
                                            Wf, bf, (float*)d_out, cnts);
}

// Round 11
// 979.930 us; speedup vs baseline: 2.5405x; 1.1994x over previous
//
#include <hip/hip_runtime.h>
#include <math.h>

// Problem constants
constexpr int B  = 32;
constexpr int T  = 24;
constexpr int D  = 13;
constexpr int N  = 1024;   // 32*32 spatial
constexpr int SZ = B * D * N;
constexpr int HPW = B * N * 16 / 2;   // hp size in floats (bf16 [B][N][16])

typedef __attribute__((ext_vector_type(8))) short bf16x8;
typedef __attribute__((ext_vector_type(4))) float f32x4;

__device__ __forceinline__ float sigmoidf_(float x) { return 1.f / (1.f + __expf(-x)); }
__device__ __forceinline__ float tanhf_(float x) {
    float e = __expf(2.f * x);
    return 1.f - 2.f / (e + 1.f);
}
__device__ __forceinline__ unsigned short f2bf(float f) {
    unsigned u = __float_as_uint(f);
    u += 0x8000u;
    return (unsigned short)(u >> 16);
}
__device__ __forceinline__ unsigned pk2bf(float lo, float hi) {
    unsigned a = __float_as_uint(lo) + 0x8000u;
    unsigned b = __float_as_uint(hi) + 0x8000u;
    return __builtin_amdgcn_perm(b, a, 0x07060302u);
}

// ---- agent-scope (sc1, L2-bypass) accessors for cross-block data ----
__device__ __forceinline__ uint4 aload16(const unsigned short* p) {
    const unsigned long long* q = (const unsigned long long*)p;
    unsigned long long a = __hip_atomic_load(q,     __ATOMIC_RELAXED, __HIP_MEMORY_SCOPE_AGENT);
    unsigned long long b = __hip_atomic_load(q + 1, __ATOMIC_RELAXED, __HIP_MEMORY_SCOPE_AGENT);
    uint4 r;
    r.x = (unsigned)a; r.y = (unsigned)(a >> 32);
    r.z = (unsigned)b; r.w = (unsigned)(b >> 32);
    return r;
}
__device__ __forceinline__ void astore16(unsigned short* p, uint4 v) {
    unsigned long long* q = (unsigned long long*)p;
    unsigned long long a = ((unsigned long long)v.y << 32) | v.x;
    unsigned long long b = ((unsigned long long)v.w << 32) | v.z;
    __hip_atomic_store(q,     a, __ATOMIC_RELAXED, __HIP_MEMORY_SCOPE_AGENT);
    __hip_atomic_store(q + 1, b, __ATOMIC_RELAXED, __HIP_MEMORY_SCOPE_AGENT);
}
__device__ __forceinline__ void astore2(unsigned short* p, unsigned short v) {
    __hip_atomic_store(p, v, __ATOMIC_RELAXED, __HIP_MEMORY_SCOPE_AGENT);
}

// PER-BATCH fence-free barrier: only the 16 blocks of batch `by` sync.
// Batches drift independently; CU co-residents are different batches, so
// barrier wait is hidden by the other block's compute. No release/acquire
// fences: cross-block data travels via sc1 (L3), and __syncthreads drains
// vmcnt before the signal.
__device__ __forceinline__ void gsync(unsigned* cnts, int by, unsigned k) {
    __syncthreads();
    if (threadIdx.x == 0) {
        unsigned* c1 = cnts + by * 16;   // 64 B apart: no false sharing
        __hip_atomic_fetch_add(c1, 1u, __ATOMIC_RELAXED, __HIP_MEMORY_SCOPE_AGENT);
        while (__hip_atomic_load(c1, __ATOMIC_RELAXED, __HIP_MEMORY_SCOPE_AGENT) < 16u * k)
            __builtin_amdgcn_s_sleep(2);
    }
    __syncthreads();
}

// ---------------------------------------------------------------- zero init
__global__ void k_zero(float* __restrict__ p, int n) {
    int i = blockIdx.x * 256 + threadIdx.x;
    if (i < n) p[i] = 0.f;
}

// ---------------------------------------------------------------- x1 -> packed bf16 [b][t][pix][16] (one-time)
__global__ __launch_bounds__(256) void k_xprep(const float* __restrict__ x1,
                                               unsigned short* __restrict__ x1p) {
    int i = blockIdx.x * 256 + threadIdx.x;
    int pix = i & 1023, bt = i >> 10;
    const float* src = x1 + (size_t)bt * D * N + pix;
    unsigned short tmp[16];
#pragma unroll
    for (int d = 0; d < 13; ++d) tmp[d] = f2bf(src[(size_t)d * N]);
    tmp[13] = tmp[14] = tmp[15] = 0;
    uint4* dst = (uint4*)(x1p + (size_t)i * 16);
    dst[0] = ((const uint4*)tmp)[0];
    dst[1] = ((const uint4*)tmp)[1];
}

// ---------------------------------------------------------------- conv weights -> MFMA A-fragment layout (bf16)
__global__ void k_wprep(const float* __restrict__ Wg, unsigned short* __restrict__ wrA) {
    int i = blockIdx.x * 256 + threadIdx.x;
    if (i >= 4 * 9 * 64 * 8) return;
    int j = i & 7; int r = i >> 3;
    int lane = r & 63; r >>= 6;
    int tap = r % 9; int ct = r / 9;
    int m = lane & 15, g = lane >> 4;
    int k = g * 8 + j;
    int co = ct * 16 + m;
    int ci = -1;
    if (k < 13) ci = k;
    else if (k >= 16 && k < 29) ci = k - 3;
    unsigned short v = 0;
    if (co < 52 && ci >= 0) v = f2bf(Wg[(co * 26 + ci) * 9 + tap]);
    wrA[i] = v;
}

// LDS union: CP phase and ATTN phase reuse the same region
struct __align__(16) SharedCP {
    unsigned short s_in[136 * 32];   // 8704 B
    float s_g[52 * 65];              // 13520 B
    float s_ht[13 * 64];
    float s_mv[13 * 64];
};
struct __align__(16) SharedAT {
    unsigned short s_k[2 * 128 * 24];  // 12288 B
    unsigned short s_v[2 * 16 * 136];  // 8704 B
    unsigned short s_hout[64 * 16];    // 2048 B
    float s_hf[13 * 65];
    float s_zh[13 * 65];
    float s_zm[13 * 65];
    float s_zc[13 * 65];
};
union SharedU { SharedCP cp; SharedAT at; };

// ---------------------------------------------------------------- persistent fused sequence kernel
// grid (16,32) = 512 blocks co-resident (2/CU). Block (bx,by) owns pixels
// [64bx,64bx+64) of batch by in BOTH phases -> c/m/qT/h_tmp block-private
// (normal loads, L2-resident — no fences anywhere). Cross-block data (K/V, hp)
// goes through L3 via sc1 accessors. Barriers are PER-BATCH (16 blocks).
__global__ __launch_bounds__(256, 2) void k_seq(
    const unsigned short* __restrict__ x1p, const unsigned short* __restrict__ wrA,
    float* __restrict__ c, float* __restrict__ m, unsigned short* __restrict__ hp,
    float* __restrict__ h_tmp, unsigned short* __restrict__ qT,
    unsigned short* __restrict__ khT, unsigned short* __restrict__ kmT,
    unsigned short* __restrict__ vhb, unsigned short* __restrict__ vmb,
    const float* __restrict__ Wq, const float* __restrict__ Wkh, const float* __restrict__ Wvh,
    const float* __restrict__ Wkm, const float* __restrict__ Wvm,
    const float* __restrict__ Wz, const float* __restrict__ Wm,
    const float* __restrict__ Wf, const float* __restrict__ bfin,
    float* __restrict__ out, unsigned* __restrict__ cnts)
{
    __shared__ SharedU u;
    __shared__ float s_wz[13 * 26];
    __shared__ float s_wm[39 * 26];

    const int bx = blockIdx.x, by = blockIdx.y;
    const int tid = threadIdx.x;
    const int w = __builtin_amdgcn_readfirstlane(tid >> 6);
    const int lane = tid & 63;
    const int g = lane >> 4, l15 = lane & 15;
    const size_t bb = (size_t)by * D * N;

    for (int idx = tid; idx < 13 * 26; idx += 256) s_wz[idx] = Wz[idx];
    for (int idx = tid; idx < 39 * 26; idx += 256) s_wm[idx] = Wm[idx];

    unsigned kk = 0;

    for (int t = 0; t < T; ++t) {
        // ================= CP PHASE =================
        {
            unsigned short* s_in = u.cp.s_in;
            float* s_g  = u.cp.s_g;
            float* s_ht = u.cp.s_ht;
            float* s_mv = u.cp.s_mv;
            const int y = bx * 2 + (lane >> 5), x = lane & 31;
            const int pix = y * 32 + x;

            float cpre[4], mpre[4];
#pragma unroll
            for (int i2 = 0; i2 < 4; ++i2) {
                int dd = w + 4 * i2;
                if (dd < 13) {
                    cpre[i2] = c[bb + (size_t)dd * N + pix];
                    mpre[i2] = m[bb + (size_t)dd * N + pix];
                } else { cpre[i2] = 0.f; mpre[i2] = 0.f; }
            }
            bf16x8 af[9];
#pragma unroll
            for (int tap = 0; tap < 9; ++tap)
                af[tap] = *(const bf16x8*)&wrA[(((size_t)w * 9 + tap) * 64 + lane) * 8];

            // stage input tile: x1p normal loads, hp via sc1 (cross-block halo)
            if (tid < 136) {
                int row = tid / 34, col = tid % 34;
                int gy = bx * 2 - 1 + row, gx = col - 1;
                bool ok = ((unsigned)gy < 32u) && ((unsigned)gx < 32u);
                uint4 z = {0, 0, 0, 0};
                uint4 a0 = z, a1 = z, b0 = z, b1 = z;
                if (ok) {
                    const int off = gy * 32 + gx;
                    const uint4* xs = (const uint4*)(x1p + (((size_t)by * T + t) * N + off) * 16);
                    a0 = xs[0]; a1 = xs[1];
                    const unsigned short* hsp = hp + ((size_t)by * N + off) * 16;
                    b0 = aload16(hsp);
                    b1 = aload16(hsp + 8);
                }
                uint4* dst = (uint4*)&s_in[tid * 32];
                dst[0] = a0; dst[1] = a1; dst[2] = b0; dst[3] = b1;
            }
            __syncthreads();

            f32x4 acc[4];
#pragma unroll
            for (int pt = 0; pt < 4; ++pt) acc[pt] = f32x4{0.f, 0.f, 0.f, 0.f};
#pragma unroll
            for (int pt = 0; pt < 4; ++pt) {
                const int px = pt * 16 + l15;
                const int r0 = px >> 5, c0 = px & 31;
#pragma unroll
                for (int tap = 0; tap < 9; ++tap) {
                    const int srow = r0 + tap / 3, scol = c0 + tap % 3;
                    bf16x8 bfr = *(const bf16x8*)&s_in[(srow * 34 + scol) * 32 + 8 * g];
                    acc[pt] = __builtin_amdgcn_mfma_f32_16x16x32_bf16(af[tap], bfr, acc[pt], 0, 0, 0);
                }
            }
#pragma unroll
            for (int pt = 0; pt < 4; ++pt) {
#pragma unroll
                for (int rr = 0; rr < 4; ++rr) {
                    const int co = w * 16 + 4 * g + rr;
                    if (co < 52) s_g[co * 65 + pt * 16 + l15] = acc[pt][rr];
                }
            }
            __syncthreads();

#pragma unroll
            for (int i2 = 0; i2 < 4; ++i2) {
                int dd = w + 4 * i2;
                if (dd < 13) {
                    float ig = sigmoidf_(s_g[dd * 65 + lane]);
                    float fg = sigmoidf_(s_g[(13 + dd) * 65 + lane]);
                    float gg = tanhf_(s_g[(26 + dd) * 65 + lane]);
                    float og = sigmoidf_(s_g[(39 + dd) * 65 + lane]);
                    const size_t gi = bb + (size_t)dd * N + pix;
                    float cn = fg * cpre[i2] + ig * gg;
                    c[gi] = cn;
                    float hv = og * tanhf_(cn);
                    h_tmp[gi] = hv;
                    s_ht[dd * 64 + lane] = hv;
                    s_mv[dd * 64 + lane] = mpre[i2];
                }
            }
            __syncthreads();

            const size_t ro = ((size_t)by * N + pix) * 16;
            if (w == 0) {               // q -> qT (private; log2e folded)
                float htv[13];
#pragma unroll
                for (int j = 0; j < 13; ++j) htv[j] = s_ht[j * 64 + lane];
                float o[13];
#pragma unroll
                for (int d = 0; d < 13; ++d) {
                    float a = 0.f;
#pragma unroll
                    for (int j = 0; j < 13; ++j) a = fmaf(Wq[d * 13 + j], htv[j], a);
                    o[d] = a * 1.44269504089f;
                }
                uint4 w0, w1;
                w0.x = pk2bf(o[0], o[1]);  w0.y = pk2bf(o[2], o[3]);
                w0.z = pk2bf(o[4], o[5]);  w0.w = pk2bf(o[6], o[7]);
                w1.x = pk2bf(o[8], o[9]);  w1.y = pk2bf(o[10], o[11]);
                w1.z = pk2bf(o[12], 0.f);  w1.w = 0u;
                ((uint4*)(qT + ro))[0] = w0; ((uint4*)(qT + ro))[1] = w1;
            } else if (w == 1) {        // kh/vh -> sc1 stores (cross-block)
                float htv[13];
#pragma unroll
                for (int j = 0; j < 13; ++j) htv[j] = s_ht[j * 64 + lane];
                float o[13];
#pragma unroll
                for (int d = 0; d < 13; ++d) {
                    float a = 0.f;
#pragma unroll
                    for (int j = 0; j < 13; ++j) a = fmaf(Wkh[d * 13 + j], htv[j], a);
                    o[d] = a;
                }
                uint4 w0, w1;
                w0.x = pk2bf(o[0], o[1]);  w0.y = pk2bf(o[2], o[3]);
                w0.z = pk2bf(o[4], o[5]);  w0.w = pk2bf(o[6], o[7]);
                w1.x = pk2bf(o[8], o[9]);  w1.y = pk2bf(o[10], o[11]);
                w1.z = pk2bf(o[12], 0.f);  w1.w = 0u;
                astore16(khT + ro, w0); astore16(khT + ro + 8, w1);
#pragma unroll
                for (int d = 0; d < 13; ++d) {
                    float a = 0.f;
#pragma unroll
                    for (int j = 0; j < 13; ++j) a = fmaf(Wvh[d * 13 + j], htv[j], a);
                    astore2(vhb + bb + (size_t)d * N + pix, f2bf(a));
                }
            } else if (w == 2) {        // km/vm -> sc1 stores
                float mvv[13];
#pragma unroll
                for (int j = 0; j < 13; ++j) mvv[j] = s_mv[j * 64 + lane];
                float o[13];
#pragma unroll
                for (int d = 0; d < 13; ++d) {
                    float a = 0.f;
#pragma unroll
                    for (int j = 0; j < 13; ++j) a = fmaf(Wkm[d * 13 + j], mvv[j], a);
                    o[d] = a;
                }
                uint4 w0, w1;
                w0.x = pk2bf(o[0], o[1]);  w0.y = pk2bf(o[2], o[3]);
                w0.z = pk2bf(o[4], o[5]);  w0.w = pk2bf(o[6], o[7]);
                w1.x = pk2bf(o[8], o[9]);  w1.y = pk2bf(o[10], o[11]);
                w1.z = pk2bf(o[12], 0.f);  w1.w = 0u;
                astore16(kmT + ro, w0); astore16(kmT + ro + 8, w1);
#pragma unroll
                for (int d = 0; d < 13; ++d) {
                    float a = 0.f;
#pragma unroll
                    for (int j = 0; j < 13; ++j) a = fmaf(Wvm[d * 13 + j], mvv[j], a);
                    astore2(vmb + bb + (size_t)d * N + pix, f2bf(a));
                }
            }
        }

        if (t == T - 1) break;

        ++kk; gsync(cnts, by, kk);   // sync A (per-batch): K/V at L3

        // ================= ATTN PHASE (64 queries, single K/V pass) =================
        {
            unsigned short* s_k = u.at.s_k;
            unsigned short* s_v = u.at.s_v;
            unsigned short* s_hout = u.at.s_hout;
            float* s_hf = u.at.s_hf;
            float* s_zh = u.at.s_zh;
            float* s_zm = u.at.s_zm;
            float* s_zc = u.at.s_zc;
            const int br = w >> 1, qg = w & 1;
            const int n0 = bx * 64;

            const int rowk = tid >> 1, partk = tid & 1;
            const unsigned short* kb0 = khT + ((size_t)by * N + rowk) * 16 + partk * 8;
            const unsigned short* kb1 = kmT + ((size_t)by * N + rowk) * 16 + partk * 8;
            unsigned short* sk0 = &s_k[rowk * 24 + partk * 8];
            unsigned short* sk1 = &s_k[3072 + rowk * 24 + partk * 8];
            const int brv0 = (tid >= 208) ? 1 : 0;
            const int rem0 = tid - 208 * brv0;
            const int dv0 = rem0 >> 4, pv0 = rem0 & 15;
            const unsigned short* vb0 = (brv0 ? vmb : vhb) + bb + (size_t)dv0 * N + pv0 * 8;
            unsigned short* sv0 = &s_v[brv0 * 2176 + dv0 * 136 + pv0 * 8];
            const bool doV1 = (tid < 160);
            const int rem1 = tid + 48;
            const int dv1 = rem1 >> 4, pv1 = rem1 & 15;
            const unsigned short* vb1 = vmb + bb + (size_t)dv1 * N + pv1 * 8;
            unsigned short* sv1 = &s_v[2176 + dv1 * 136 + pv1 * 8];

            uint4 rk0 = aload16(kb0);
            uint4 rk1 = aload16(kb1);
            uint4 rv0 = aload16(vb0);
            uint4 rv1 = doV1 ? aload16(vb1) : uint4{0, 0, 0, 0};

            for (int idx = tid; idx < 832; idx += 256) {
                int d = idx >> 6, p = idx & 63;
                s_hf[d * 65 + p] = h_tmp[bb + (size_t)d * N + n0 + p];
            }
            for (int idx = tid; idx < 1024; idx += 256) s_hout[idx] = 0;
            for (int idx = tid; idx < 2 * 3 * 136; idx += 256) {
                int keyp = idx % 136;
                int r = idx / 136;
                int row = r % 3, br2 = r / 3;
                s_v[br2 * 2176 + (13 + row) * 136 + keyp] =
                    (row == 0) ? (unsigned short)0x3F80 : (unsigned short)0;
            }

            bf16x8 b1a = {0, 0, 0, 0, 0, 0, 0, 0}, b1b = {0, 0, 0, 0, 0, 0, 0, 0};
            if (g < 2) {
                b1a = *(const bf16x8*)(qT + ((size_t)by * N + n0 + qg * 16 + l15) * 16 + 8 * g);
                b1b = *(const bf16x8*)(qT + ((size_t)by * N + n0 + (qg + 2) * 16 + l15) * 16 + 8 * g);
            }

            f32x4 zacca = {0.f, 0.f, 0.f, 0.f}, zaccb = {0.f, 0.f, 0.f, 0.f};

            for (int cc = 0; cc < 8; ++cc) {
                if (cc) __syncthreads();
                *(uint4*)sk0 = rk0;
                *(uint4*)sk1 = rk1;
                *(uint4*)sv0 = rv0;
                if (doV1) *(uint4*)sv1 = rv1;
                __syncthreads();
                if (cc < 7) {
                    const size_t ko = (size_t)(cc + 1) * 128 * 16;
                    const size_t vo = (size_t)(cc + 1) * 128;
                    rk0 = aload16(kb0 + ko);
                    rk1 = aload16(kb1 + ko);
                    rv0 = aload16(vb0 + vo);
                    if (doV1) rv1 = aload16(vb1 + vo);
                }
#pragma unroll
                for (int uu = 0; uu < 4; ++uu) {
                    bf16x8 a0 = {0, 0, 0, 0, 0, 0, 0, 0}, a1v = {0, 0, 0, 0, 0, 0, 0, 0};
                    if (g < 2) {
                        const int rbase = 32 * uu + 8 * (l15 >> 2) + (l15 & 3);
                        a0  = *(const bf16x8*)&s_k[br * 3072 + (rbase)     * 24 + 8 * g];
                        a1v = *(const bf16x8*)&s_k[br * 3072 + (rbase + 4) * 24 + 8 * g];
                    }
                    bf16x8 a2 = *(const bf16x8*)&s_v[br * 2176 + l15 * 136 + 32 * uu + 8 * g];

                    {   // group A
                        f32x4 d0 = {0.f, 0.f, 0.f, 0.f}, d1 = {0.f, 0.f, 0.f, 0.f};
                        d0 = __builtin_amdgcn_mfma_f32_16x16x32_bf16(a0,  b1a, d0, 0, 0, 0);
                        d1 = __builtin_amdgcn_mfma_f32_16x16x32_bf16(a1v, b1a, d1, 0, 0, 0);
                        float e0[4], e1[4];
#pragma unroll
                        for (int r = 0; r < 4; ++r) { e0[r] = exp2f(d0[r]); e1[r] = exp2f(d1[r]); }
                        union { int4 iv; bf16x8 v; } u2;
                        u2.iv.x = (int)pk2bf(e0[0], e0[1]);
                        u2.iv.y = (int)pk2bf(e0[2], e0[3]);
                        u2.iv.z = (int)pk2bf(e1[0], e1[1]);
                        u2.iv.w = (int)pk2bf(e1[2], e1[3]);
                        zacca = __builtin_amdgcn_mfma_f32_16x16x32_bf16(a2, u2.v, zacca, 0, 0, 0);
                    }
                    {   // group B
                        f32x4 d0 = {0.f, 0.f, 0.f, 0.f}, d1 = {0.f, 0.f, 0.f, 0.f};
                        d0 = __builtin_amdgcn_mfma_f32_16x16x32_bf16(a0,  b1b, d0, 0, 0, 0);
                        d1 = __builtin_amdgcn_mfma_f32_16x16x32_bf16(a1v, b1b, d1, 0, 0, 0);
                        float e0[4], e1[4];
#pragma unroll
                        for (int r = 0; r < 4; ++r) { e0[r] = exp2f(d0[r]); e1[r] = exp2f(d1[r]); }
                        union { int4 iv; bf16x8 v; } u2;
                        u2.iv.x = (int)pk2bf(e0[0], e0[1]);
                        u2.iv.y = (int)pk2bf(e0[2], e0[3]);
                        u2.iv.z = (int)pk2bf(e1[0], e1[1]);
                        u2.iv.w = (int)pk2bf(e1[2], e1[3]);
                        zaccb = __builtin_amdgcn_mfma_f32_16x16x32_bf16(a2, u2.v, zaccb, 0, 0, 0);
                    }
                }
            }

            const float denA = __shfl(zacca[1], 48 + l15, 64);
            const float denB = __shfl(zaccb[1], 48 + l15, 64);
            const float rdA = 1.f / denA, rdB = 1.f / denB;

            float* zs = br ? s_zm : s_zh;
#pragma unroll
            for (int r = 0; r < 4; ++r) {
                int d = 4 * g + r;
                if (d < 13) {
                    zs[d * 65 + qg * 16 + l15]       = zacca[r] * rdA;
                    zs[d * 65 + (qg + 2) * 16 + l15] = zaccb[r] * rdB;
                }
            }
            __syncthreads();

            for (int idx = tid; idx < 832; idx += 256) {
                int d = idx >> 6, p = idx & 63;
                float a = 0.f;
#pragma unroll
                for (int ci = 0; ci < 13; ++ci)
                    a += s_wz[d * 26 + ci] * s_zh[ci * 65 + p]
                       + s_wz[d * 26 + 13 + ci] * s_zm[ci * 65 + p];
                s_zc[d * 65 + p] = a;
            }
            __syncthreads();

            for (int idx = tid; idx < 832; idx += 256) {
                int d = idx >> 6, p = idx & 63;
                float mo = 0.f, mg = 0.f, mi = 0.f;
#pragma unroll
                for (int ci = 0; ci < 13; ++ci) {
                    float zc = s_zc[ci * 65 + p];
                    mo += s_wm[d * 26 + ci] * zc;
                    mg += s_wm[(13 + d) * 26 + ci] * zc;
                    mi += s_wm[(26 + d) * 26 + ci] * zc;
                }
#pragma unroll
                for (int ci = 0; ci < 13; ++ci) {
                    float hc = s_hf[ci * 65 + p];
                    mo += s_wm[d * 26 + 13 + ci] * hc;
                    mg += s_wm[(13 + d) * 26 + 13 + ci] * hc;
                    mi += s_wm[(26 + d) * 26 + 13 + ci] * hc;
                }
                mi = sigmoidf_(mi);
                const size_t gi = bb + (size_t)d * N + n0 + p;
                float mn = (1.f - mi) * m[gi] + mi * tanhf_(mg);
                m[gi] = mn;
                s_hout[p * 16 + d] = f2bf(sigmoidf_(mo) * mn);
            }
            __syncthreads();

            if (tid < 64) {   // hp via sc1 (read cross-block next step)
                unsigned short* dst = hp + ((size_t)by * N + n0 + tid) * 16;
                const uint4* srcp = (const uint4*)&s_hout[tid * 16];
                astore16(dst, srcp[0]);
                astore16(dst + 8, srcp[1]);
            }
        }

        ++kk; gsync(cnts, by, kk);   // sync B (per-batch): hp at L3
    }

    // ================= FINAL: 1x1 conv + log_softmax (c block-private) =================
    __syncthreads();
    if (tid < 64) {
        const int px = bx * 64 + tid;
        const size_t base = bb + px;
        float cv[13];
#pragma unroll
        for (int d = 0; d < 13; ++d) cv[d] = c[base + (size_t)d * N];
        float lg[8]; float mx = -1e30f;
#pragma unroll
        for (int k = 0; k < 8; ++k) {
            float a = bfin[k];
#pragma unroll
            for (int d = 0; d < 13; ++d) a += Wf[k * 13 + d] * cv[d];
            lg[k] = a; mx = fmaxf(mx, a);
        }
        float s = 0.f;
#pragma unroll
        for (int k = 0; k < 8; ++k) s += __expf(lg[k] - mx);
        float lse = mx + logf(s);
        const size_t ob = (size_t)by * 8 * N + px;
#pragma unroll
        for (int k = 0; k < 8; ++k) out[ob + (size_t)k * N] = lg[k] - lse;
    }
}

// ---------------------------------------------------------------- host launcher
extern "C" void kernel_launch(void* const* d_in, const int* in_sizes, int n_in,
                              void* d_out, int out_size, void* d_ws, size_t ws_size,
                              hipStream_t stream) {
    const float* x1  = (const float*)d_in[0];
    const float* Wg  = (const float*)d_in[1];
    const float* Wq  = (const float*)d_in[2];
    const float* Wkh = (const float*)d_in[3];
    const float* Wvh = (const float*)d_in[4];
    const float* Wkm = (const float*)d_in[5];
    const float* Wvm = (const float*)d_in[6];
    const float* Wz  = (const float*)d_in[7];
    const float* Wm  = (const float*)d_in[8];
    const float* Wf  = (const float*)d_in[9];
    const float* bf  = (const float*)d_in[10];

    float* ws = (float*)d_ws;
    unsigned* cnts = (unsigned*)d_ws;                       // ws[0..1024): counters
    float* c   = ws + 1024;
    float* m   = c + (size_t)SZ;
    unsigned short* hp = (unsigned short*)(m + (size_t)SZ); // [B][N][16] bf16
    float* h_tmp = (float*)(hp + (size_t)2 * HPW);

    unsigned short* qT  = (unsigned short*)(h_tmp + (size_t)SZ);
    unsigned short* khT = qT  + (size_t)16 * B * N;         // [B][N][16]
    unsigned short* kmT = khT + (size_t)16 * B * N;
    unsigned short* vhb = kmT + (size_t)16 * B * N;         // [B][13][N]
    unsigned short* vmb = vhb + (size_t)13 * B * N;
    unsigned short* x1p = vmb + (size_t)13 * B * N;         // [B][T][N][16]
    unsigned short* wrA = x1p + (size_t)16 * B * T * N;

    const int zn = 1024 + 2 * SZ + HPW;    // counters + c + m + hp
    k_zero<<<(zn + 255) / 256, 256, 0, stream>>>(ws, zn);
    k_wprep<<<72, 256, 0, stream>>>(Wg, wrA);
    k_xprep<<<(B * T * N) / 256, 256, 0, stream>>>(x1, x1p);

    k_seq<<<dim3(16, 32), 256, 0, stream>>>(x1p, wrA, c, m, hp, h_tmp,
                                            qT, khT, kmT, vhb, vmb,
                                            Wq, Wkh, Wvh, Wkm, Wvm, Wz, Wm,
                                            Wf, bf, (float*)d_out, cnts);
}